// Round 9
// baseline (1372.060 us; speedup 1.0000x reference)
//
#include <hip/hip_runtime.h>
#include <math.h>

// TfLSTM: x[512,256,128] -> LSTM(100, relu) -> LSTM(128, relu, last) -> Dense(19) -> softmax
// Round 9: r8 structure + two surgical fixes:
//  (1) LDS-only barrier in the recurrence loop (asm lgkmcnt(0)+s_barrier):
//      __syncthreads() forces s_waitcnt vmcnt(0) before s_barrier, draining the
//      zn prefetch + h1seq stores EVERY step (~600-900 cyc of the measured
//      ~4000 cyc/step). Only LDS (h double-buffer) needs barrier ordering.
//  (2) waves_per_eu(1,2): min=1 -> 512-reg allocator budget (r5/r7-proven);
//      r8's (2,2) left VGPR_Count=124 < the 128 B-frag regs (remat signature).
// Math identical to r8 (verified absmax 0.0).

#define T_SEQ 256
#define BATCH 512
#define IN_DIM 128
#define H1 100
#define H2 128
#define NCLS 19

typedef float f4v __attribute__((ext_vector_type(4)));
typedef short s8v __attribute__((ext_vector_type(8)));

#define FOR_GA(M) M(0) M(1) M(2) M(3)

__device__ __forceinline__ void lds_barrier_() {
    // barrier with LDS-only drain: global loads/stores stay in flight
    __asm__ volatile("s_waitcnt lgkmcnt(0)\n\ts_barrier" ::: "memory");
}

__device__ __forceinline__ float sigmoidf_(float x) {
    return 1.0f / (1.0f + __expf(-x));
}
__device__ __forceinline__ f4v sig4_(f4v z) {
    f4v r;
    r.x = sigmoidf_(z.x); r.y = sigmoidf_(z.y);
    r.z = sigmoidf_(z.z); r.w = sigmoidf_(z.w);
    return r;
}
__device__ __forceinline__ f4v relu4_(f4v z) {
    f4v r;
    r.x = fmaxf(z.x, 0.f); r.y = fmaxf(z.y, 0.f);
    r.z = fmaxf(z.z, 0.f); r.w = fmaxf(z.w, 0.f);
    return r;
}
// RNE fp32->bf16 + exact hi float
__device__ __forceinline__ short bf_hi_(float x, float& hif) {
    unsigned u = __builtin_bit_cast(unsigned, x);
    unsigned r = (u + 0x7FFFu + ((u >> 16) & 1u)) & 0xFFFF0000u;
    hif = __builtin_bit_cast(float, r);
    return (short)(r >> 16);
}
__device__ __forceinline__ void bsplit_(float x, short& hi, short& lo) {
    float hif;
    hi = bf_hi_(x, hif);
    float rs = x - hif;
    float d;
    lo = bf_hi_(rs, d);
}
__device__ __forceinline__ float bf2f_(short s) {
    unsigned v = ((unsigned)(unsigned short)s) << 16;
    return __builtin_bit_cast(float, v);
}
// B-frag: B[k = kt*32+lq*8+j][col = ga*NU+u]; PAD remaps into U1[100][400].
template<bool PAD>
__device__ __forceinline__ void load_bf_(const float* __restrict__ U,
                                         int u, int ga, int kt, int lq,
                                         s8v& hi, s8v& lo) {
    short h, l;
#pragma unroll
    for (int j = 0; j < 8; ++j) {
        int k = kt * 32 + lq * 8 + j;
        float x;
        if (PAD) x = (u < 100 && k < 100) ? U[(size_t)k * 400 + ga * 100 + u] : 0.0f;
        else     x = U[(size_t)k * 512 + ga * 128 + u];
        bsplit_(x, h, l);
        hi[j] = h; lo[j] = l;
    }
}

// =================== in-register-gate MFMA recurrence (8-wave) ===================
// Block: 16 batch rows, 512 threads, grid 32. Wave w: units u = 16w+lm, 4 gates.
template<bool PAD, bool SEQOUT, bool INIT, bool WROUT>
__global__ __launch_bounds__(512)
__attribute__((amdgpu_waves_per_eu(1, 2)))
void recg_kernel(const float* __restrict__ zx,    // [tlen][B][512] (bias incl)
                 const float* __restrict__ U,     // PAD ? [100][400] : [128][512]
                 float* __restrict__ outp,        // SEQOUT: h1seq chunk [t][B][100]; WROUT: h2 [B][128]
                 float* __restrict__ cbuf,        // [B][128] c carry
                 float* __restrict__ hbuf,        // [B][128] h carry
                 int tlen)
{
    constexpr int HLD = 136;             // shorts per row (272 B = 17*16, b128-aligned)
    constexpr int HSZ = 16 * HLD;
    __shared__ __align__(16) short hsH[2][HSZ];  // h hi-bf16, double-buffered
    __shared__ __align__(16) short hsL[2][HSZ];  // h lo-bf16

    const int tid = threadIdx.x;
    const int wv = tid >> 6;             // 0..7: unit group
    const int lane = tid & 63;
    const int lm = lane & 15;
    const int lq = lane >> 4;
    const int u = 16 * wv + lm;          // unit owned by this lane
    const int blk16 = blockIdx.x * 16;

    // ---- one-time B-frag load: 4 gates x 4 ktiles x (hi,lo) = 128 VGPRs ----
#define BDECL(ga) \
    s8v bh##ga##_0, bl##ga##_0, bh##ga##_1, bl##ga##_1, \
        bh##ga##_2, bl##ga##_2, bh##ga##_3, bl##ga##_3; \
    load_bf_<PAD>(U, u, ga, 0, lq, bh##ga##_0, bl##ga##_0); \
    load_bf_<PAD>(U, u, ga, 1, lq, bh##ga##_1, bl##ga##_1); \
    load_bf_<PAD>(U, u, ga, 2, lq, bh##ga##_2, bl##ga##_2); \
    load_bf_<PAD>(U, u, ga, 3, lq, bh##ga##_3, bl##ga##_3);
    FOR_GA(BDECL)
#undef BDECL

    // ---- init h(0) into buffer 0 (pre-split) ----
    if (INIT) {
        for (int i = tid; i < HSZ; i += 512) { hsH[0][i] = 0; hsL[0][i] = 0; }
    } else {
        int row = tid >> 5, c4 = (tid & 31) * 4;   // 512 thr cover 16x128 f4-wise
        f4v hvv = *(const f4v*)&hbuf[(size_t)(blk16 + row) * 128 + c4];
        short hb, lb;
        bsplit_(hvv.x, hb, lb); hsH[0][row * HLD + c4 + 0] = hb; hsL[0][row * HLD + c4 + 0] = lb;
        bsplit_(hvv.y, hb, lb); hsH[0][row * HLD + c4 + 1] = hb; hsL[0][row * HLD + c4 + 1] = lb;
        bsplit_(hvv.z, hb, lb); hsH[0][row * HLD + c4 + 2] = hb; hsL[0][row * HLD + c4 + 2] = lb;
        bsplit_(hvv.w, hb, lb); hsH[0][row * HLD + c4 + 3] = hb; hsL[0][row * HLD + c4 + 3] = lb;
    }
    // ---- c state: rows lq*4+r, unit u ----
    f4v cst = {0.f, 0.f, 0.f, 0.f};
    if (!INIT) {
        const float* pc = cbuf + (size_t)(blk16 + lq * 4) * 128 + u;
        cst = (f4v){pc[0], pc[128], pc[256], pc[384]};
    }
    // ---- zc = zx(t=0) ----
    f4v zc0, zc1, zc2, zc3, zn0, zn1, zn2, zn3;
#define ZLD(ga, tt, dst) { \
    const float* p = zx + ((size_t)(tt) * BATCH + blk16 + lq * 4) * 512 + (ga) * 128 + u; \
    dst##ga = (f4v){p[0], p[512], p[1024], p[1536]}; }
    ZLD(0, 0, zc) ZLD(1, 0, zc) ZLD(2, 0, zc) ZLD(3, 0, zc)
    __syncthreads();

#define MKT(kt) { \
    const s8v ah = *(const s8v*)&hsH[cur][lm * HLD + (kt) * 32 + lq * 8]; \
    const s8v al = *(const s8v*)&hsL[cur][lm * HLD + (kt) * 32 + lq * 8]; \
    ac0 = __builtin_amdgcn_mfma_f32_16x16x32_bf16(ah, bh0_##kt, ac0, 0, 0, 0); \
    ac0 = __builtin_amdgcn_mfma_f32_16x16x32_bf16(al, bh0_##kt, ac0, 0, 0, 0); \
    ac0 = __builtin_amdgcn_mfma_f32_16x16x32_bf16(ah, bl0_##kt, ac0, 0, 0, 0); \
    ac1 = __builtin_amdgcn_mfma_f32_16x16x32_bf16(ah, bh1_##kt, ac1, 0, 0, 0); \
    ac1 = __builtin_amdgcn_mfma_f32_16x16x32_bf16(al, bh1_##kt, ac1, 0, 0, 0); \
    ac1 = __builtin_amdgcn_mfma_f32_16x16x32_bf16(ah, bl1_##kt, ac1, 0, 0, 0); \
    ac2 = __builtin_amdgcn_mfma_f32_16x16x32_bf16(ah, bh2_##kt, ac2, 0, 0, 0); \
    ac2 = __builtin_amdgcn_mfma_f32_16x16x32_bf16(al, bh2_##kt, ac2, 0, 0, 0); \
    ac2 = __builtin_amdgcn_mfma_f32_16x16x32_bf16(ah, bl2_##kt, ac2, 0, 0, 0); \
    ac3 = __builtin_amdgcn_mfma_f32_16x16x32_bf16(ah, bh3_##kt, ac3, 0, 0, 0); \
    ac3 = __builtin_amdgcn_mfma_f32_16x16x32_bf16(al, bh3_##kt, ac3, 0, 0, 0); \
    ac3 = __builtin_amdgcn_mfma_f32_16x16x32_bf16(ah, bl3_##kt, ac3, 0, 0, 0); }

#pragma unroll 1
    for (int t = 0; t < tlen; ++t) {
        const int cur = t & 1, nxt = cur ^ 1;
        // zn prefetch (stays in flight across the LDS-only barrier)
        int tn = (t + 1 < tlen) ? t + 1 : t;
        ZLD(0, tn, zn) ZLD(1, tn, zn) ZLD(2, tn, zn) ZLD(3, tn, zn)
        // MFMA: 4 gate slots, acc init = zc
        f4v ac0 = zc0, ac1 = zc1, ac2 = zc2, ac3 = zc3;
        MKT(0) MKT(1) MKT(2) MKT(3)
        // gates fully in registers
        f4v iv = sig4_(ac0), fv = sig4_(ac1), gv = relu4_(ac2), ov = sig4_(ac3);
        cst = fv * cst + iv * gv;
        f4v hv = ov * relu4_(cst);
        // split + store h (pre-split) to next buffer
        short hb, lb;
        bsplit_(hv.x, hb, lb); hsH[nxt][(lq * 4 + 0) * HLD + u] = hb; hsL[nxt][(lq * 4 + 0) * HLD + u] = lb;
        bsplit_(hv.y, hb, lb); hsH[nxt][(lq * 4 + 1) * HLD + u] = hb; hsL[nxt][(lq * 4 + 1) * HLD + u] = lb;
        bsplit_(hv.z, hb, lb); hsH[nxt][(lq * 4 + 2) * HLD + u] = hb; hsL[nxt][(lq * 4 + 2) * HLD + u] = lb;
        bsplit_(hv.w, hb, lb); hsH[nxt][(lq * 4 + 3) * HLD + u] = hb; hsL[nxt][(lq * 4 + 3) * HLD + u] = lb;
        if (SEQOUT) {
            if (!PAD || u < 100) {
                float* po = outp + ((size_t)t * BATCH + blk16 + lq * 4) * 100 + u;
                po[0] = hv.x; po[100] = hv.y; po[200] = hv.z; po[300] = hv.w;
            }
        }
        lds_barrier_();   // LDS-only drain: zn loads + h1seq stores keep flying
        zc0 = zn0; zc1 = zn1; zc2 = zn2; zc3 = zn3;
    }
#undef MKT
#undef ZLD

    // ---- chunk carry + outputs (h reconstructed hi+lo) ----
    const int fin = tlen & 1;
    {
        int row = tid >> 5, c4 = (tid & 31) * 4;
        f4v hvv;
        hvv.x = bf2f_(hsH[fin][row * HLD + c4 + 0]) + bf2f_(hsL[fin][row * HLD + c4 + 0]);
        hvv.y = bf2f_(hsH[fin][row * HLD + c4 + 1]) + bf2f_(hsL[fin][row * HLD + c4 + 1]);
        hvv.z = bf2f_(hsH[fin][row * HLD + c4 + 2]) + bf2f_(hsL[fin][row * HLD + c4 + 2]);
        hvv.w = bf2f_(hsH[fin][row * HLD + c4 + 3]) + bf2f_(hsL[fin][row * HLD + c4 + 3]);
        *(f4v*)&hbuf[(size_t)(blk16 + row) * 128 + c4] = hvv;
        if (WROUT) *(f4v*)&outp[(size_t)(blk16 + row) * 128 + c4] = hvv;
    }
    {
        float* pc = cbuf + (size_t)(blk16 + lq * 4) * 128 + u;
        pc[0] = cst.x; pc[128] = cst.y; pc[256] = cst.z; pc[384] = cst.w;
    }
}

// =================== layer-1 projection, gate-padded output ===================
__global__ __launch_bounds__(256, 2)
void proj1p_kernel(const float* __restrict__ x, const float* __restrict__ W1,
                   const float* __restrict__ b1, float* __restrict__ out, int t0)
{
    constexpr int LD = 132;
    __shared__ __align__(16) float As[32 * LD];
    __shared__ __align__(16) float Ws[32 * LD];
    const int tid = threadIdx.x;
    const int b = blockIdx.x;
    const int c0 = blockIdx.y * 128;
    const int ty = tid >> 4, tx = tid & 15;
    const float* A = x + ((size_t)b * T_SEQ + t0) * IN_DIM;

#define PACC(i) f4v accL##i = {0.f,0.f,0.f,0.f}; f4v accR##i = {0.f,0.f,0.f,0.f};
    PACC(0) PACC(1) PACC(2) PACC(3) PACC(4) PACC(5) PACC(6) PACC(7)
#undef PACC

    for (int kk = 0; kk < IN_DIM; kk += 32) {
        __syncthreads();
#pragma unroll
        for (int i = 0; i < 4; ++i) {
            int idx = tid + i * 256;
            int row = idx >> 3, kg = idx & 7;
            int k = kk + kg * 4;
            f4v v = *(const f4v*)&A[(size_t)row * IN_DIM + k];
            As[(kg * 4 + 0) * LD + row] = v.x;
            As[(kg * 4 + 1) * LD + row] = v.y;
            As[(kg * 4 + 2) * LD + row] = v.z;
            As[(kg * 4 + 3) * LD + row] = v.w;
        }
#pragma unroll
        for (int i = 0; i < 4; ++i) {
            int idx = tid + i * 256;
            int k = idx >> 5, cg = idx & 31;
            int gk = kk + k;
            int gcp = c0 + cg * 4;
            int gate = gcp >> 7, ub = gcp & 127;
            f4v v;
            v.x = (ub + 0 < 100) ? W1[(size_t)gk * 400 + gate * 100 + ub + 0] : 0.f;
            v.y = (ub + 1 < 100) ? W1[(size_t)gk * 400 + gate * 100 + ub + 1] : 0.f;
            v.z = (ub + 2 < 100) ? W1[(size_t)gk * 400 + gate * 100 + ub + 2] : 0.f;
            v.w = (ub + 3 < 100) ? W1[(size_t)gk * 400 + gate * 100 + ub + 3] : 0.f;
            *(f4v*)&Ws[k * LD + cg * 4] = v;
        }
        __syncthreads();
#pragma unroll
        for (int k = 0; k < 32; ++k) {
            f4v av0 = *(const f4v*)&As[k * LD + ty * 8];
            f4v av1 = *(const f4v*)&As[k * LD + ty * 8 + 4];
            f4v b0v = *(const f4v*)&Ws[k * LD + tx * 8];
            f4v b1v = *(const f4v*)&Ws[k * LD + tx * 8 + 4];
#define PFMA(i, s) accL##i += (s) * b0v; accR##i += (s) * b1v;
            PFMA(0, av0.x) PFMA(1, av0.y) PFMA(2, av0.z) PFMA(3, av0.w)
            PFMA(4, av1.x) PFMA(5, av1.y) PFMA(6, av1.z) PFMA(7, av1.w)
#undef PFMA
        }
    }

    const int cb = c0 + tx * 8;
    f4v bL, bR;
#pragma unroll
    for (int j = 0; j < 4; ++j) {
        int gate = (cb + j) >> 7, uu = (cb + j) & 127;
        bL[j] = (uu < 100) ? b1[gate * 100 + uu] : 0.f;
    }
#pragma unroll
    for (int j = 0; j < 4; ++j) {
        int gate = (cb + 4 + j) >> 7, uu = (cb + 4 + j) & 127;
        bR[j] = (uu < 100) ? b1[gate * 100 + uu] : 0.f;
    }
#define PST(i) { \
        int tl = ty * 8 + i; \
        size_t orow = (size_t)tl * BATCH + b; \
        f4v vL = accL##i + bL; *(f4v*)&out[orow * 512 + cb] = vL; \
        f4v vR = accR##i + bR; *(f4v*)&out[orow * 512 + cb + 4] = vR; }
    PST(0) PST(1) PST(2) PST(3) PST(4) PST(5) PST(6) PST(7)
#undef PST
}

// =================== generic projection GEMM (layer 2) ===================
#define PREP8(M)  M(0) M(1) M(2) M(3) M(4) M(5) M(6) M(7)
template<int K, int N, bool SWAP>
__global__ __launch_bounds__(256, 2)
void proj_kernel(const float* __restrict__ A, const float* __restrict__ W,
                 const float* __restrict__ bias, float* __restrict__ out)
{
    constexpr int LD = 132;
    __shared__ __align__(16) float As[32 * LD];
    __shared__ __align__(16) float Ws[32 * LD];
    const int tid = threadIdx.x;
    const int r0 = blockIdx.x * 128;
    const int c0 = blockIdx.y * 128;
    const int ty = tid >> 4, tx = tid & 15;

#define PACC(i) f4v accL##i = {0.f,0.f,0.f,0.f}; f4v accR##i = {0.f,0.f,0.f,0.f};
    PREP8(PACC)
#undef PACC

    for (int kk = 0; kk < K; kk += 32) {
        __syncthreads();
#pragma unroll
        for (int i = 0; i < 4; ++i) {
            int idx = tid + i * 256;
            int row = idx >> 3, kg = idx & 7;
            int k = kk + kg * 4;
            f4v v = {0.f, 0.f, 0.f, 0.f};
            if (k < K) v = *(const f4v*)&A[(size_t)(r0 + row) * K + k];
            As[(kg * 4 + 0) * LD + row] = v.x;
            As[(kg * 4 + 1) * LD + row] = v.y;
            As[(kg * 4 + 2) * LD + row] = v.z;
            As[(kg * 4 + 3) * LD + row] = v.w;
        }
#pragma unroll
        for (int i = 0; i < 4; ++i) {
            int idx = tid + i * 256;
            int k = idx >> 5, cg = idx & 31;
            int gk = kk + k, gc = c0 + cg * 4;
            f4v v = {0.f, 0.f, 0.f, 0.f};
            if (gk < K && gc < N) v = *(const f4v*)&W[(size_t)gk * N + gc];
            *(f4v*)&Ws[k * LD + cg * 4] = v;
        }
        __syncthreads();
#pragma unroll
        for (int k = 0; k < 32; ++k) {
            f4v av0 = *(const f4v*)&As[k * LD + ty * 8];
            f4v av1 = *(const f4v*)&As[k * LD + ty * 8 + 4];
            f4v b0v = *(const f4v*)&Ws[k * LD + tx * 8];
            f4v b1v = *(const f4v*)&Ws[k * LD + tx * 8 + 4];
#define PFMA(i, s) accL##i += (s) * b0v; accR##i += (s) * b1v;
            PFMA(0, av0.x) PFMA(1, av0.y) PFMA(2, av0.z) PFMA(3, av0.w)
            PFMA(4, av1.x) PFMA(5, av1.y) PFMA(6, av1.z) PFMA(7, av1.w)
#undef PFMA
        }
    }

    const int cb = c0 + tx * 8;
    f4v bL, bR;
#pragma unroll
    for (int j = 0; j < 4; ++j) bL[j] = (cb + j < N) ? bias[cb + j] : 0.f;
#pragma unroll
    for (int j = 0; j < 4; ++j) bR[j] = (cb + 4 + j < N) ? bias[cb + 4 + j] : 0.f;
#define PST(i) { \
        int r = r0 + ty * 8 + i; \
        size_t orow = SWAP ? ((size_t)(r & 255) * BATCH + (r >> 8)) : (size_t)r; \
        if (cb < N)     { f4v v = accL##i + bL; *(f4v*)&out[orow * N + cb] = v; } \
        if (cb + 4 < N) { f4v v = accR##i + bR; *(f4v*)&out[orow * N + cb + 4] = v; } }
    PREP8(PST)
#undef PST
}

// =================== dense + softmax ===================
__global__ __launch_bounds__(64, 1)
void dense_softmax_kernel(const float* __restrict__ h2, const float* __restrict__ Wd,
                          const float* __restrict__ bd, float* __restrict__ out)
{
    const int b = blockIdx.x;
    const int k = threadIdx.x;
    __shared__ __align__(16) float hsm[H2];
    if (k < H2 / 4) ((f4v*)hsm)[k] = ((const f4v*)(h2 + (size_t)b * H2))[k];
    __syncthreads();

    float logit = -1e30f;
    if (k < NCLS) {
        float acc = bd[k];
#pragma unroll
        for (int d = 0; d < H2; ++d) acc += hsm[d] * Wd[d * NCLS + k];
        logit = acc;
    }
    float m = logit;
#pragma unroll
    for (int off = 32; off >= 1; off >>= 1) m = fmaxf(m, __shfl_xor(m, off, 64));
    float e = (k < NCLS) ? __expf(logit - m) : 0.0f;
    float s = e;
#pragma unroll
    for (int off = 32; off >= 1; off >>= 1) s += __shfl_xor(s, off, 64);
    if (k < NCLS) out[(size_t)b * NCLS + k] = e / s;
}

// =================== fallback (round-1) kernels ===================
__global__ __launch_bounds__(448, 1)
void lstm1_fb(const float* __restrict__ x, const float* __restrict__ W1,
              const float* __restrict__ U1, const float* __restrict__ b1,
              float* __restrict__ h1out)
{
    const int b = blockIdx.x;
    const int k = threadIdx.x;
    __shared__ __align__(16) float xs[IN_DIM];
    __shared__ __align__(16) float hs[H1];
    __shared__ __align__(16) float zs[4 * H1];
    float w1r[IN_DIM];
    float u1r[H1];
    float bias = 0.0f;
    if (k < 4 * H1) {
        bias = b1[k];
#pragma unroll
        for (int d = 0; d < IN_DIM; ++d) w1r[d] = W1[d * (4 * H1) + k];
#pragma unroll
        for (int j = 0; j < H1; ++j) u1r[j] = U1[j * (4 * H1) + k];
    }
    if (k < H1) hs[k] = 0.0f;
    if (k < IN_DIM / 4)
        ((float4*)xs)[k] = ((const float4*)(x + ((size_t)b * T_SEQ) * IN_DIM))[k];
    float c = 0.0f;
    __syncthreads();
    for (int t = 0; t < T_SEQ; ++t) {
        if (k < 4 * H1) {
            float acc0 = bias, acc1 = 0.f, acc2 = 0.f, acc3 = 0.f;
#pragma unroll
            for (int q = 0; q < IN_DIM / 4; ++q) {
                float4 xv = ((const float4*)xs)[q];
                acc0 += xv.x * w1r[4 * q]; acc1 += xv.y * w1r[4 * q + 1];
                acc2 += xv.z * w1r[4 * q + 2]; acc3 += xv.w * w1r[4 * q + 3];
            }
#pragma unroll
            for (int q = 0; q < H1 / 4; ++q) {
                float4 hv = ((const float4*)hs)[q];
                acc0 += hv.x * u1r[4 * q]; acc1 += hv.y * u1r[4 * q + 1];
                acc2 += hv.z * u1r[4 * q + 2]; acc3 += hv.w * u1r[4 * q + 3];
            }
            float zv = (acc0 + acc1) + (acc2 + acc3);
            zs[k] = (k >= 2 * H1 && k < 3 * H1) ? fmaxf(zv, 0.0f) : sigmoidf_(zv);
        }
        __syncthreads();
        if (k < H1) {
            float i = zs[k], f = zs[k + H1], g = zs[k + 2 * H1], o = zs[k + 3 * H1];
            c = f * c + i * g;
            float h = o * fmaxf(c, 0.0f);
            hs[k] = h;
            h1out[((size_t)t * BATCH + b) * H1 + k] = h;
        }
        int tn = t + 1;
        if (tn < T_SEQ && k < IN_DIM / 4)
            ((float4*)xs)[k] = ((const float4*)(x + ((size_t)b * T_SEQ + tn) * IN_DIM))[k];
        __syncthreads();
    }
}

__global__ __launch_bounds__(512, 1)
void lstm2_fb(const float* __restrict__ h1in, const float* __restrict__ W2,
              const float* __restrict__ U2, const float* __restrict__ b2,
              float* __restrict__ h2out)
{
    const int b = blockIdx.x;
    const int k = threadIdx.x;
    __shared__ __align__(16) float ps[H1];
    __shared__ __align__(16) float hs[H2];
    __shared__ __align__(16) float zs[4 * H2];
    float w2r[H1];
    float u2r[H2];
    float bias = b2[k];
#pragma unroll
    for (int j = 0; j < H1; ++j) w2r[j] = W2[j * (4 * H2) + k];
#pragma unroll
    for (int j = 0; j < H2; ++j) u2r[j] = U2[j * (4 * H2) + k];
    if (k < H2) hs[k] = 0.0f;
    if (k < H1 / 4)
        ((float4*)ps)[k] = ((const float4*)(h1in + (size_t)b * H1))[k];
    float c = 0.0f;
    float hlast = 0.0f;
    __syncthreads();
    for (int t = 0; t < T_SEQ; ++t) {
        float acc0 = bias, acc1 = 0.f, acc2 = 0.f, acc3 = 0.f;
#pragma unroll
        for (int q = 0; q < H1 / 4; ++q) {
            float4 pv = ((const float4*)ps)[q];
            acc0 += pv.x * w2r[4 * q]; acc1 += pv.y * w2r[4 * q + 1];
            acc2 += pv.z * w2r[4 * q + 2]; acc3 += pv.w * w2r[4 * q + 3];
        }
#pragma unroll
        for (int q = 0; q < H2 / 4; ++q) {
            float4 hv = ((const float4*)hs)[q];
            acc0 += hv.x * u2r[4 * q]; acc1 += hv.y * u2r[4 * q + 1];
            acc2 += hv.z * u2r[4 * q + 2]; acc3 += hv.w * u2r[4 * q + 3];
        }
        float zv = (acc0 + acc1) + (acc2 + acc3);
        zs[k] = (k >= 2 * H2 && k < 3 * H2) ? fmaxf(zv, 0.0f) : sigmoidf_(zv);
        __syncthreads();
        if (k < H2) {
            float i = zs[k], f = zs[k + H2], g = zs[k + 2 * H2], o = zs[k + 3 * H2];
            c = f * c + i * g;
            hlast = o * fmaxf(c, 0.0f);
            hs[k] = hlast;
        }
        int tn = t + 1;
        if (tn < T_SEQ && k < H1 / 4)
            ((float4*)ps)[k] = ((const float4*)(h1in + ((size_t)tn * BATCH + b) * H1))[k];
        __syncthreads();
    }
    if (k < H2) h2out[(size_t)b * H2 + k] = hlast;
}

extern "C" void kernel_launch(void* const* d_in, const int* in_sizes, int n_in,
                              void* d_out, int out_size, void* d_ws, size_t ws_size,
                              hipStream_t stream) {
    const float* x  = (const float*)d_in[0];
    const float* W1 = (const float*)d_in[1];
    const float* U1 = (const float*)d_in[2];
    const float* b1 = (const float*)d_in[3];
    const float* W2 = (const float*)d_in[4];
    const float* U2 = (const float*)d_in[5];
    const float* b2 = (const float*)d_in[6];
    const float* Wd = (const float*)d_in[7];
    const float* bd = (const float*)d_in[8];
    float* out = (float*)d_out;

    const int TC = T_SEQ / 2;                                   // 128-step chunks
    const size_t zx_elems = (size_t)TC * BATCH * 512;           // 134.2 MB
    const size_t h1_elems = (size_t)T_SEQ * BATCH * H1;         // 52.4 MB
    const size_t st_elems = (size_t)BATCH * H2;
    const size_t need = (zx_elems + h1_elems + 5 * st_elems) * sizeof(float);  // ~188 MB

    if (ws_size >= need) {
        float* zxbuf = (float*)d_ws;
        float* h1buf = zxbuf + zx_elems;
        float* c1buf = h1buf + h1_elems;
        float* hc1buf = c1buf + st_elems;
        float* c2buf = hc1buf + st_elems;
        float* hc2buf = c2buf + st_elems;
        float* h2buf = hc2buf + st_elems;

        // ---- layer 1, chunk A (t 0..127) ----
        hipLaunchKernelGGL(proj1p_kernel, dim3(BATCH, 4), dim3(256), 0, stream,
                           x, W1, b1, zxbuf, 0);
        hipLaunchKernelGGL((recg_kernel<true, true, true, false>), dim3(32), dim3(512), 0, stream,
                           zxbuf, U1, h1buf, c1buf, hc1buf, TC);
        // ---- layer 1, chunk B (t 128..255) ----
        hipLaunchKernelGGL(proj1p_kernel, dim3(BATCH, 4), dim3(256), 0, stream,
                           x, W1, b1, zxbuf, TC);
        hipLaunchKernelGGL((recg_kernel<true, true, false, false>), dim3(32), dim3(512), 0, stream,
                           zxbuf, U1, h1buf + (size_t)TC * BATCH * H1, c1buf, hc1buf, TC);
        // ---- layer 2, chunk A ----
        hipLaunchKernelGGL((proj_kernel<H1, 4 * H2, false>), dim3(512, 4), dim3(256), 0, stream,
                           h1buf, W2, b2, zxbuf);
        hipLaunchKernelGGL((recg_kernel<false, false, true, false>), dim3(32), dim3(512), 0, stream,
                           zxbuf, U2, (float*)nullptr, c2buf, hc2buf, TC);
        // ---- layer 2, chunk B ----
        hipLaunchKernelGGL((proj_kernel<H1, 4 * H2, false>), dim3(512, 4), dim3(256), 0, stream,
                           h1buf + (size_t)TC * BATCH * H1, W2, b2, zxbuf);
        hipLaunchKernelGGL((recg_kernel<false, false, false, true>), dim3(32), dim3(512), 0, stream,
                           zxbuf, U2, h2buf, c2buf, hc2buf, TC);

        hipLaunchKernelGGL(dense_softmax_kernel, dim3(BATCH), dim3(64), 0, stream,
                           h2buf, Wd, bd, out);
    } else {
        // fallback: round-1 fused kernels (needs ~52.7 MB)
        float* h1buf = (float*)d_ws;
        float* h2buf = h1buf + h1_elems;
        hipLaunchKernelGGL(lstm1_fb, dim3(BATCH), dim3(448), 0, stream, x, W1, U1, b1, h1buf);
        hipLaunchKernelGGL(lstm2_fb, dim3(BATCH), dim3(512), 0, stream, h1buf, W2, U2, b2, h2buf);
        hipLaunchKernelGGL(dense_softmax_kernel, dim3(BATCH), dim3(64), 0, stream, h2buf, Wd, bd, out);
    }
}